// Round 3
// baseline (75.435 us; speedup 1.0000x reference)
//
#include <hip/hip_runtime.h>
#include <math.h>

#define B_ 8
#define N_ 128
#define L_ 30
#define D_ 256
#define NEGV -1000000000.0f
#define SCALE 0.0625f   // 1/sqrt(256)
#define ROWS 4

// ---------------- Kernel 1: k = f_w @ Wk^T + bk  (B*L rows) ----------------
__global__ __launch_bounds__(256) void k_proj(const float* __restrict__ f_w,
    const float* __restrict__ Wk, const float* __restrict__ bk,
    float* __restrict__ k_out) {
  int bl = blockIdx.x;          // b*L + l
  int d  = threadIdx.x;         // 0..255
  __shared__ float fw[D_];
  fw[d] = f_w[bl * D_ + d];
  __syncthreads();
  const float4* wrow = (const float4*)(Wk + (size_t)d * D_);
  float acc = 0.f;
#pragma unroll 8
  for (int j = 0; j < D_ / 4; ++j) {
    float4 w = wrow[j];
    acc += w.x * fw[4*j+0] + w.y * fw[4*j+1] + w.z * fw[4*j+2] + w.w * fw[4*j+3];
  }
  k_out[bl * D_ + d] = acc + bk[d];
}

// ---- Kernel 2: q-proj + aw softmax (over L) + f_baq + f_bq, 4 n-rows/block ----
__global__ __launch_bounds__(256) void qk_fbq(const float* __restrict__ f_b,
    const float* __restrict__ f_w, const float* __restrict__ f_s,
    const float* __restrict__ qmask, const float* __restrict__ lmask,
    const float* __restrict__ Wq, const float* __restrict__ bq,
    const float* __restrict__ kmat, float* __restrict__ f_bq) {
  int blk = blockIdx.x;
  int b   = blk / (N_ / ROWS);
  int n0  = (blk % (N_ / ROWS)) * ROWS;
  int d   = threadIdx.x;

  __shared__ float fb[ROWS][D_];        // broadcast reads only
  __shared__ float qs[ROWS][D_ + 1];    // padded
  __shared__ float aw[ROWS][L_ + 2];

  for (int r = 0; r < ROWS; ++r)
    fb[r][d] = f_b[(size_t)(b * N_ + n0 + r) * D_ + d];
  __syncthreads();

  float qacc[ROWS];
#pragma unroll
  for (int r = 0; r < ROWS; ++r) qacc[r] = 0.f;
  const float4* wrow = (const float4*)(Wq + (size_t)d * D_);
  for (int j = 0; j < D_ / 4; ++j) {
    float4 w = wrow[j];
#pragma unroll
    for (int r = 0; r < ROWS; ++r)
      qacc[r] += w.x*fb[r][4*j] + w.y*fb[r][4*j+1] + w.z*fb[r][4*j+2] + w.w*fb[r][4*j+3];
  }
  float bqd = bq[d];
#pragma unroll
  for (int r = 0; r < ROWS; ++r) qs[r][d] = qacc[r] + bqd;
  __syncthreads();

  if (d < ROWS * L_) {
    int r = d / L_, l = d % L_;
    const float4* krow = (const float4*)(kmat + (size_t)(b * L_ + l) * D_);
    float acc = 0.f;
    for (int j = 0; j < D_ / 4; ++j) {
      float4 kv = krow[j];
      acc += kv.x*qs[r][4*j] + kv.y*qs[r][4*j+1] + kv.z*qs[r][4*j+2] + kv.w*qs[r][4*j+3];
    }
    float qm = qmask[b * L_ + l];
    aw[r][l] = (qm == 0.f) ? NEGV : acc * SCALE * qm;
  }
  __syncthreads();

  if (d < ROWS) {
    int r = d;
    float mx = -1e30f;
    for (int l = 0; l < L_; ++l) mx = fmaxf(mx, aw[r][l]);
    float s = 0.f;
    for (int l = 0; l < L_; ++l) { float e = __expf(aw[r][l] - mx); aw[r][l] = e; s += e; }
    float inv = 1.f / s;
    for (int l = 0; l < L_; ++l) aw[r][l] *= inv;
  }
  __syncthreads();

  float facc[ROWS];
#pragma unroll
  for (int r = 0; r < ROWS; ++r) facc[r] = 0.f;
  for (int l = 0; l < L_; ++l) {
    float fwv = f_w[(size_t)(b * L_ + l) * D_ + d];
#pragma unroll
    for (int r = 0; r < ROWS; ++r) facc[r] += aw[r][l] * fwv;
  }
  float fsd = f_s[b * D_ + d];
#pragma unroll
  for (int r = 0; r < ROWS; ++r) {
    float lm = lmask[b * N_ + n0 + r];
    f_bq[(size_t)(b * N_ + n0 + r) * D_ + d] = fb[r][d] * (facc[r] * lm + fsd);
  }
}

// ---- Kernel 3 (fused): f_m preload -> A-row softmax -> f_bb -> sigmoid stream ----
// out[n,:] = f_b[n] + lmn*sum_m A[n,m]*f_b[m] + sum_m A[n,m]*sigmoid(fm*fs)*fm
__global__ __launch_bounds__(512) void fused_final(const float* __restrict__ f_b,
    const float* __restrict__ f_m, const float* __restrict__ f_s,
    const float* __restrict__ lmask, const float* __restrict__ f_bq,
    float* __restrict__ out) {
  int bn = blockIdx.x;            // b*N + n
  int b  = bn >> 7;
  int n  = bn & 127;
  int t  = threadIdx.x;           // 0..511
  int wave = t >> 6;              // 0..7
  int lane = t & 63;

  __shared__ float qn[D_];
  __shared__ float part[N_][5];   // [m][quarter], padded
  __shared__ float a_lds[N_];
  __shared__ float sm[8];
  __shared__ float4 red[7][64];
  __shared__ float fbbred[2][D_];

  // ---- Preload this wave's 16 f_m rows (issued before everything else).
  const float4* fmbase = (const float4*)(f_m + (size_t)bn * N_ * D_);
  int m0 = wave * 16;
  float4 pre[16];
#pragma unroll
  for (int i = 0; i < 16; ++i)
    pre[i] = fmbase[(size_t)(m0 + i) * (D_ / 4) + lane];
  __builtin_amdgcn_sched_barrier(0);   // pin: loads stay issued up here

  // ---- Phase A: A-row = softmax(f_bq[n].f_bq[m]*scale, masked) * lmask[n]
  if (t < D_) qn[t] = f_bq[(size_t)bn * D_ + t];
  __syncthreads();

  {
    int m = t >> 2, q = t & 3;    // 4 threads per m-row, 64 floats each
    const float4* rowp = (const float4*)(f_bq + (size_t)(b * N_ + m) * D_ + q * 64);
    const float4* qp   = (const float4*)(qn + q * 64);
    float acc = 0.f;
#pragma unroll
    for (int j = 0; j < 16; ++j) {
      float4 v = rowp[j]; float4 qv = qp[j];
      acc += v.x*qv.x + v.y*qv.y + v.z*qv.z + v.w*qv.w;
    }
    part[m][q] = acc;
  }
  __syncthreads();

  float myval = NEGV;
  if (t < N_) {
    float s = part[t][0] + part[t][1] + part[t][2] + part[t][3];
    float lm = lmask[b * N_ + t];
    myval = (lm == 0.f) ? NEGV : s * SCALE * lm;
    float mx = myval;
#pragma unroll
    for (int off = 32; off >= 1; off >>= 1) mx = fmaxf(mx, __shfl_xor(mx, off));
    if (lane == 0) sm[wave] = mx;
  }
  __syncthreads();
  float e = 0.f;
  if (t < N_) {
    float gmax = fmaxf(sm[0], sm[1]);
    e = __expf(myval - gmax);
    float ssum = e;
#pragma unroll
    for (int off = 32; off >= 1; off >>= 1) ssum += __shfl_xor(ssum, off);
    if (lane == 0) sm[4 + wave] = ssum;
  }
  __syncthreads();
  float lmn = lmask[b * N_ + n];
  if (t < N_) {
    float tot = sm[4] + sm[5];
    a_lds[t] = e * (lmn / tot);
  }
  __syncthreads();

  // ---- Phase B: f_bb partial = sum_m a[m]*f_b[m][d]  (L2-resident column walk)
  {
    int d = t & 255, half = t >> 8;
    const float* fbcol = f_b + (size_t)b * N_ * D_ + d;
    float acc = 0.f;
    int mm0 = half * 64;
#pragma unroll 8
    for (int i = 0; i < 64; ++i) {
      int m = mm0 + i;
      acc += a_lds[m] * fbcol[(size_t)m * D_];
    }
    fbbred[half][d] = acc;
  }

  // ---- Phase C: sigmoid-gated f_m accumulation (pure register math)
  float4 fs4 = ((const float4*)(f_s + (size_t)b * D_))[lane];
  float4 acc = make_float4(0.f, 0.f, 0.f, 0.f);
  const float C = -1.44269504088896f;   // -log2(e)
#pragma unroll
  for (int i = 0; i < 16; ++i) {
    float a = a_lds[m0 + i];
    float4 fm = pre[i];
    float gx = __builtin_amdgcn_rcpf(1.f + __builtin_amdgcn_exp2f(fm.x * fs4.x * C));
    float gy = __builtin_amdgcn_rcpf(1.f + __builtin_amdgcn_exp2f(fm.y * fs4.y * C));
    float gz = __builtin_amdgcn_rcpf(1.f + __builtin_amdgcn_exp2f(fm.z * fs4.z * C));
    float gw = __builtin_amdgcn_rcpf(1.f + __builtin_amdgcn_exp2f(fm.w * fs4.w * C));
    acc.x += a * (gx * fm.x);
    acc.y += a * (gy * fm.y);
    acc.z += a * (gz * fm.z);
    acc.w += a * (gw * fm.w);
  }

  if (wave > 0) red[wave - 1][lane] = acc;
  __syncthreads();
  if (wave == 0) {
#pragma unroll
    for (int j = 0; j < 7; ++j) {
      float4 r4 = red[j][lane];
      acc.x += r4.x; acc.y += r4.y; acc.z += r4.z; acc.w += r4.w;
    }
    const float4* fbbase = (const float4*)(f_b + (size_t)b * N_ * D_);
    float4 fbn = fbbase[(size_t)n * (D_ / 4) + lane];
    float4 bb0 = ((const float4*)fbbred[0])[lane];
    float4 bb1 = ((const float4*)fbbred[1])[lane];
    float4 o;
    o.x = fbn.x + acc.x + lmn * (bb0.x + bb1.x);
    o.y = fbn.y + acc.y + lmn * (bb0.y + bb1.y);
    o.z = fbn.z + acc.z + lmn * (bb0.z + bb1.z);
    o.w = fbn.w + acc.w + lmn * (bb0.w + bb1.w);
    ((float4*)out)[(size_t)bn * (D_ / 4) + lane] = o;
  }
}

extern "C" void kernel_launch(void* const* d_in, const int* in_sizes, int n_in,
                              void* d_out, int out_size, void* d_ws, size_t ws_size,
                              hipStream_t stream) {
  const float* f_b   = (const float*)d_in[0];
  const float* f_w   = (const float*)d_in[1];
  const float* f_s   = (const float*)d_in[2];
  const float* f_m   = (const float*)d_in[3];
  const float* qmask = (const float*)d_in[4];
  const float* lmask = (const float*)d_in[5];
  const float* Wq    = (const float*)d_in[6];
  const float* bq    = (const float*)d_in[7];
  const float* Wk    = (const float*)d_in[8];
  const float* bk    = (const float*)d_in[9];
  float* out = (float*)d_out;

  float* ws   = (float*)d_ws;
  float* kmat = ws;                       // 240*256      = 61440 floats
  float* fbq  = ws + 65536;               // 1024*256     = 262144 floats

  hipLaunchKernelGGL(k_proj, dim3(B_ * L_), dim3(256), 0, stream, f_w, Wk, bk, kmat);
  hipLaunchKernelGGL(qk_fbq, dim3(B_ * N_ / ROWS), dim3(256), 0, stream,
                     f_b, f_w, f_s, qmask, lmask, Wq, bq, kmat, fbq);
  hipLaunchKernelGGL(fused_final, dim3(B_ * N_), dim3(512), 0, stream,
                     f_b, f_m, f_s, lmask, fbq, out);
}